// Round 10
// baseline (161.763 us; speedup 1.0000x reference)
//
#include <hip/hip_runtime.h>

// Problem constants
#define DD 64
#define LL 50
#define NB 4096
#define NT 100

typedef __attribute__((ext_vector_type(8))) __bf16 bf16x8;
typedef __attribute__((ext_vector_type(4))) float f32x4;

__device__ __forceinline__ float sigmoidf_(float x) {
    return 1.0f / (1.0f + __expf(-x));
}
// round-half-up f32->bf16, pack two into one u32 (hi -> upper 16)
__device__ __forceinline__ unsigned pack_bf16(float hi, float lo) {
    union { float f; unsigned u; } a, b;
    a.f = hi; b.f = lo;
    return ((a.u + 0x8000u) & 0xffff0000u) | ((b.u + 0x8000u) >> 16);
}
__device__ __forceinline__ uint4 cvt8u(const float* f) {
    uint4 r;
    r.x = pack_bf16(f[1], f[0]);
    r.y = pack_bf16(f[3], f[2]);
    r.z = pack_bf16(f[5], f[4]);
    r.w = pack_bf16(f[7], f[6]);
    return r;
}
__device__ __forceinline__ bf16x8 cvt8(const float* f) {
    return __builtin_bit_cast(bf16x8, cvt8u(f));
}
// async global->LDS: wave-uniform LDS base + lane*size (gfx950)
__device__ __forceinline__ void glds16(const float* g, float* l) {
    __builtin_amdgcn_global_load_lds(
        (const __attribute__((address_space(1))) void*)g,
        (__attribute__((address_space(3))) void*)l, 16, 0, 0);
}
__device__ __forceinline__ void glds4(const float* g, float* l) {
    __builtin_amdgcn_global_load_lds(
        (const __attribute__((address_space(1))) void*)g,
        (__attribute__((address_space(3))) void*)l, 4, 0, 0);
}

// ===========================================================================
// K0: blocks 0..255: batched user GEMM (16 users/wave).
//     block 256: pack fg_item_W -> bf16 row-major (k1 reads frags directly).
// ===========================================================================
__global__ __launch_bounds__(64) void k0_user(
    const int* __restrict__ uid_g, const float* __restrict__ user_table,
    const float* __restrict__ Wu, const float* __restrict__ bu,
    const float* __restrict__ bi, const float* __restrict__ igu,
    const float* __restrict__ Wi,
    float* __restrict__ ufg_ws, float* __restrict__ t2_ws,
    unsigned short* __restrict__ wiB_ws)
{
    if (blockIdx.x == 256) {   // Wi -> bf16 pack
        const int n = threadIdx.x;
        float tmp[64];
#pragma unroll
        for (int c4 = 0; c4 < 16; c4++)
            *(float4*)&tmp[c4 * 4] = *(const float4*)(Wi + n * DD + c4 * 4);
#pragma unroll
        for (int ch = 0; ch < 8; ch++)
            *(uint4*)(wiB_ws + n * DD + ch * 8) = cvt8u(tmp + ch * 8);
        return;
    }

    const int lane = threadIdx.x;
    const int c = lane & 15, q = lane >> 4;
    const int uid = uid_g[blockIdx.x * 16 + c];
    const float* urow = user_table + (size_t)uid * DD;

    bf16x8 af[2];
#pragma unroll
    for (int kf = 0; kf < 2; kf++) {
        float tmp[8];
        *(float4*)&tmp[0] = *(const float4*)(urow + kf * 32 + q * 8);
        *(float4*)&tmp[4] = *(const float4*)(urow + kf * 32 + q * 8 + 4);
        af[kf] = cvt8(tmp);
    }

#pragma unroll
    for (int ni = 0; ni < 8; ni++) {
        f32x4 a = {0.f, 0.f, 0.f, 0.f};
#pragma unroll
        for (int kf = 0; kf < 2; kf++) {
            const int k0 = kf * 32 + q * 8;
            float tmp[8];
            if (ni < 4) {
                const float* src = Wu + (ni * 16 + c) * DD + k0;
                *(float4*)&tmp[0] = *(const float4*)src;
                *(float4*)&tmp[4] = *(const float4*)(src + 4);
            } else {
                const int l = ni * 16 + c - 64;
#pragma unroll
                for (int j = 0; j < 8; j++)
                    tmp[j] = (l < LL) ? igu[(k0 + j) * LL + l] : 0.f;
            }
            a = __builtin_amdgcn_mfma_f32_16x16x32_bf16(af[kf], cvt8(tmp), a, 0, 0, 0);
        }
        const int n = ni * 16 + c;
#pragma unroll
        for (int reg = 0; reg < 4; reg++) {
            const int bo = blockIdx.x * 16 + q * 4 + reg;
            if (n < DD)           ufg_ws[bo * DD + n] = a[reg] + bu[n] + bi[n];
            else if (n < DD + LL) t2_ws[bo * DD + (n - DD)] = a[reg];
        }
    }
}

// ===========================================================================
// K1: one WAVE per b, 64-thread blocks, grid 4096. (unchanged from R9)
// Item rows staged f32 into LDS via 13 async global_load_lds_dwordx4.
// ===========================================================================
__global__ __launch_bounds__(64) void k1_union(
    const int* __restrict__ uid_g, const int* __restrict__ iid_g,
    const float* __restrict__ user_table, const float* __restrict__ item_table,
    const unsigned short* __restrict__ wiB, const float* __restrict__ igi,
    const float* __restrict__ ufg_ws, const float* __restrict__ t2_ws,
    float* __restrict__ v_ws)
{
    const int lane = threadIdx.x;
    const int c = lane & 15, q = lane >> 4;
    const int b = blockIdx.x;

    __shared__ __align__(16) float sE[52 * DD + DD];   // 52 rows + t2 slot
    float* sT = sE + 52 * DD;

    // ---- ids for this lane's gather rows (13 independent loads) ----
    const int* iidp = iid_g + b * LL;
    int ids[13];
#pragma unroll
    for (int s = 0; s < 13; s++) {
        const int r = 4 * s + (lane >> 4);
        ids[s] = iidp[r < LL ? r : LL - 1];
    }

    // ---- async item gather: instr s covers rows 4s..4s+3 (256 B each) ----
    // lane i -> row r = 4s + i/16; phys chunk p = i%16 holds logical chunk
    // j = p ^ (r&7)  (XOR swizzle for bank-conflict-free readback)
#pragma unroll
    for (int s = 0; s < 13; s++) {
        const int r = 4 * s + (lane >> 4);
        const int j = (lane & 15) ^ (r & 7);
        glds16(item_table + (size_t)ids[s] * DD + j * 4, sE + s * 256);
    }
    // t2 (f32, lane-contiguous)
    glds4(t2_ws + b * DD + (lane < LL ? lane : LL - 1), sT);

    // ---- independent register loads (overlap the gather) ----
    bf16x8 wb[4][2];
#pragma unroll
    for (int ni = 0; ni < 4; ni++)
#pragma unroll
        for (int kf = 0; kf < 2; kf++)
            wb[ni][kf] = __builtin_bit_cast(bf16x8,
                *(const uint4*)(wiB + (ni * 16 + c) * DD + kf * 32 + q * 8));

    float ufg4[4], igi4[4];
#pragma unroll
    for (int ni = 0; ni < 4; ni++) {
        ufg4[ni] = ufg_ws[b * DD + ni * 16 + c];
        igi4[ni] = igi[ni * 16 + c];
    }
    const int uid = uid_g[b];
    const float u = user_table[(size_t)uid * DD + lane];

    __syncthreads();   // drains vmcnt (glds complete)

    // ---- A-frags from LDS (deswizzled), invalid rows zeroed ----
    bf16x8 ea[4][2];
#pragma unroll
    for (int mi = 0; mi < 4; mi++) {
        const int row = mi * 16 + c;
        const int rr = (row < LL) ? row : 0;
        const float* rowp = sE + rr * DD;
        const int s7 = rr & 7;
#pragma unroll
        for (int kf = 0; kf < 2; kf++) {
            float tmp[8];
            const int ch0 = (kf * 8 + 2 * q) ^ s7;
            const int ch1 = (kf * 8 + 2 * q + 1) ^ s7;
            *(float4*)&tmp[0] = *(const float4*)(rowp + ch0 * 4);
            *(float4*)&tmp[4] = *(const float4*)(rowp + ch1 * 4);
            if (row >= LL) {
#pragma unroll
                for (int i = 0; i < 8; i++) tmp[i] = 0.f;
            }
            ea[mi][kf] = cvt8(tmp);
        }
    }

    // ---- MFMA + epilogue ----
    float unum[4] = {0.f, 0.f, 0.f, 0.f};
    float sip[4]  = {0.f, 0.f, 0.f, 0.f};
    float isum = 0.f;

#pragma unroll
    for (int mi = 0; mi < 4; mi++) {
        f32x4 acc[4];
#pragma unroll
        for (int ni = 0; ni < 4; ni++) {
            f32x4 a = {0.f, 0.f, 0.f, 0.f};
            a = __builtin_amdgcn_mfma_f32_16x16x32_bf16(ea[mi][0], wb[ni][0], a, 0, 0, 0);
            a = __builtin_amdgcn_mfma_f32_16x16x32_bf16(ea[mi][1], wb[ni][1], a, 0, 0, 0);
            acc[ni] = a;
        }
        float gated[4][4], inst_r[4];
#pragma unroll
        for (int reg = 0; reg < 4; reg++) {
            const int l = mi * 16 + q * 4 + reg;
            const int valid = (l < LL);
            const int lr = valid ? l : 0;
            const int s7 = lr & 7;
            float t1 = 0.f;
#pragma unroll
            for (int ni = 0; ni < 4; ni++) {
                const int phys = (4 * ni + (c >> 2)) ^ s7;
                const float ev = sE[lr * DD + phys * 4 + (c & 3)];
                const float e = valid ? ev : 0.f;
                const float g = sigmoidf_(acc[ni][reg] + ufg4[ni]);
                const float gd = e * g;
                gated[reg][ni] = gd;
                t1 += gd * igi4[ni];
                sip[ni] += e;
            }
            t1 += __shfl_xor(t1, 1); t1 += __shfl_xor(t1, 2);
            t1 += __shfl_xor(t1, 4); t1 += __shfl_xor(t1, 8);
            inst_r[reg] = valid ? sigmoidf_(t1 + sT[lr]) : 0.f;
        }
#pragma unroll
        for (int reg = 0; reg < 4; reg++) {
            isum += inst_r[reg];
#pragma unroll
            for (int ni = 0; ni < 4; ni++)
                unum[ni] += gated[reg][ni] * inst_r[reg];
        }
    }

#pragma unroll
    for (int ni = 0; ni < 4; ni++) {
        unum[ni] += __shfl_xor(unum[ni], 16); unum[ni] += __shfl_xor(unum[ni], 32);
        sip[ni]  += __shfl_xor(sip[ni], 16);  sip[ni]  += __shfl_xor(sip[ni], 32);
    }
    isum += __shfl_xor(isum, 16); isum += __shfl_xor(isum, 32);

    // lane's d = lane = 16q + c -> take partial ni == q
    const float un = (q == 0) ? unum[0] : (q == 1) ? unum[1] : (q == 2) ? unum[2] : unum[3];
    const float si = (q == 0) ? sip[0]  : (q == 1) ? sip[1]  : (q == 2) ? sip[2]  : sip[3];
    v_ws[b * DD + lane] = u + un / isum + si;
}

// ===========================================================================
// K2: streaming scores. One block per b; 16 lanes per (b,t).
// All 7 W2 row loads hoisted (MLP); b2 load exec-masked to j==0 lanes
// (R9 had it in all lanes -> 16x the scattered-address transactions).
// ===========================================================================
__global__ __launch_bounds__(256) void k2_score(
    const int* __restrict__ tgt_g, const float* __restrict__ W2,
    const float* __restrict__ b2, const float* __restrict__ v_ws,
    float* __restrict__ out)
{
    const int b = blockIdx.x;
    const int tid = threadIdx.x;
    __shared__ float sv[DD];
    __shared__ int sids[112];
    __shared__ float sout[112];

    if (tid < DD) sv[tid] = v_ws[b * DD + tid];
    if (tid < 112) {
        const int t = (tid < NT) ? tid : NT - 1;
        sids[tid] = tgt_g[b * NT + t];
    }
    __syncthreads();

    const int j = tid & 15, g = tid >> 4;
    float4 vr = *(const float4*)&sv[j * 4];

    int id[7];
#pragma unroll
    for (int i = 0; i < 7; i++) id[i] = sids[i * 16 + g];
    float4 wv[7];
#pragma unroll
    for (int i = 0; i < 7; i++)
        wv[i] = *(const float4*)(W2 + (size_t)id[i] * DD + j * 4);

#pragma unroll
    for (int i = 0; i < 7; i++) {
        float s = wv[i].x * vr.x + wv[i].y * vr.y + wv[i].z * vr.z + wv[i].w * vr.w;
        s += __shfl_xor(s, 1); s += __shfl_xor(s, 2);
        s += __shfl_xor(s, 4); s += __shfl_xor(s, 8);
        if (j == 0) sout[i * 16 + g] = s + b2[id[i]];   // b2 load masked to 16 lanes
    }
    __syncthreads();
    if (tid < NT) out[b * NT + tid] = sout[tid];
}

// ===========================================================================
extern "C" void kernel_launch(void* const* d_in, const int* in_sizes, int n_in,
                              void* d_out, int out_size, void* d_ws, size_t ws_size,
                              hipStream_t stream)
{
    const int* user_ids        = (const int*)d_in[0];
    const int* item_seq_ids    = (const int*)d_in[1];
    const int* target_item_ids = (const int*)d_in[2];
    const float* user_tab      = (const float*)d_in[3];
    const float* item_tab      = (const float*)d_in[4];
    const float* W2_tab        = (const float*)d_in[5];
    const float* b2_tab        = (const float*)d_in[6];
    const float* fg_item_W     = (const float*)d_in[7];
    const float* fg_item_b     = (const float*)d_in[8];
    const float* fg_user_W     = (const float*)d_in[9];
    const float* fg_user_b     = (const float*)d_in[10];
    const float* igi           = (const float*)d_in[11];
    const float* igu           = (const float*)d_in[12];
    float* out = (float*)d_out;

    float* ufg_ws = (float*)d_ws;                       // [4096][64] f32
    float* t2_ws  = ufg_ws + NB * DD;                   // [4096][64] f32
    float* v_ws   = t2_ws + NB * DD;                    // [4096][64] f32
    unsigned short* wiB_ws = (unsigned short*)(v_ws + NB * DD);  // [64][64] bf16

    k0_user<<<257, 64, 0, stream>>>(user_ids, user_tab, fg_user_W, fg_user_b,
                                    fg_item_b, igu, fg_item_W,
                                    ufg_ws, t2_ws, wiB_ws);
    k1_union<<<NB, 64, 0, stream>>>(user_ids, item_seq_ids, user_tab, item_tab,
                                    wiB_ws, igi, ufg_ws, t2_ws, v_ws);
    k2_score<<<NB, 256, 0, stream>>>(target_item_ids, W2_tab, b2_tab, v_ws, out);
}